// Round 8
// baseline (227.301 us; speedup 1.0000x reference)
//
#include <hip/hip_runtime.h>

// Problem constants (B,T,C,H fixed by the reference).
constexpr int Bn = 4, Tn = 2048, Cn = 1024, Hn = 16, Dn = 64;

typedef __attribute__((ext_vector_type(8))) short short8;
typedef __attribute__((ext_vector_type(4))) float floatx4;
typedef __attribute__((ext_vector_type(2))) unsigned uint2v;
typedef __attribute__((ext_vector_type(4))) unsigned uint4v;

#define DEVFN __device__ __forceinline__

// exp(s/8) = exp2(s * log2e/8); folded into Q at GEMM1 epilogue.
constexpr float SCL = 0.18033688011112042f;

// RTNE float -> bf16 raw bits (inputs are finite; no NaN handling needed).
DEVFN unsigned f2bf_u(float f) {
  unsigned u = __builtin_bit_cast(unsigned, f);
  u += 0x7fffu + ((u >> 16) & 1u);
  return u >> 16;
}
DEVFN short f2bf(float f) { return (short)f2bf_u(f); }

// Packed RTNE f32x2 -> bf16x2 in one VALU op (no builtin on gfx950 -- T12
// primitive). R6: cutting manual pack dropped attn VALUBusy 53% -> 40%.
DEVFN unsigned cvtpk(float lo, float hi) {
  unsigned r;
  asm("v_cvt_pk_bf16_f32 %0, %1, %2" : "=v"(r) : "v"(lo), "v"(hi));
  return r;
}

DEVFN floatx4 mfma16(short8 a, short8 b, floatx4 c) {
  return __builtin_amdgcn_mfma_f32_16x16x32_bf16(a, b, c, 0, 0, 0);
}

// Async global->LDS, 16B/lane. LDS dest must be wave-uniform base + lane*16.
DEVFN void gld_lds16(const void* g, void* l) {
  __builtin_amdgcn_global_load_lds(
      (const __attribute__((address_space(1))) unsigned*)g,
      (__attribute__((address_space(3))) unsigned*)l, 16, 0, 0);
}

// ---------------------------------------------------------------- fused fp32->bf16
// One kernel casts all three inputs; destinations are contiguous in ws
// (xb | wqb | wob), so dst indexes by the global group id directly.
constexpr int G_X = 8192 * 1024 / 8;   // 1048576 groups of 8
constexpr int G_WQ = 3072 * 1024 / 8;  // 393216
constexpr int G_WO = 1024 * 1024 / 8;  // 131072
__global__ __launch_bounds__(256) void cast3_kernel(
    const float* __restrict__ x, const float* __restrict__ wq,
    const float* __restrict__ wo, short* __restrict__ dst) {
  const int i = blockIdx.x * 256 + threadIdx.x;
  const float* src;
  int rel;
  if (i < G_X) {
    src = x; rel = i;
  } else if (i < G_X + G_WQ) {
    src = wq; rel = i - G_X;
  } else {
    src = wo; rel = i - (G_X + G_WQ);
  }
  const floatx4* p = (const floatx4*)src + (size_t)rel * 2;
  floatx4 a = p[0], b = p[1];
  uint4v r;
  r[0] = cvtpk(a[0], a[1]);
  r[1] = cvtpk(a[2], a[3]);
  r[2] = cvtpk(b[0], b[1]);
  r[3] = cvtpk(b[2], b[3]);
  ((uint4v*)dst)[i] = r;
}

// ---------------------------------------------------------------- GEMM  Y = A @ B^T
// 2-phase 128x128 tile, BK=64, XOR-swizzled LDS (16B chunk ^= row&7) applied
// on the stager's GLOBAL address (fragment b128 reads conflict-free while the
// LDS side keeps gld_lds16's required uniform+lane*16 mapping).
// R1-R4 post-mortem: an 8-phase 256^2 counted-vmcnt port (m201 template) was
// tried for MODE 0 and LOST (83-107us vs 76us here): 128KB LDS -> 1 block/CU
// -> zero TLP, and at K=1024 (16 K-tiles) + 1.5 grid rounds the lockstep
// barrier chain stalls on every L2 miss. Keep the 2-phase local optimum.
// MODE 0: QKV projection. Q cols [0,1024) PRE-SCALED by log2e/8 (softmax
//         fold). Q|K -> qkb [M,2048]; V cols [2048,3072) written transposed
//         into vtb[B][H][D][T] (b64-packed: consecutive acc regs = consecutive t).
// MODE 1: output projection: fp32 out + bias.
template <int MODE>
__global__ __launch_bounds__(256, 2) void gemm_bt(
    const short* __restrict__ A, const short* __restrict__ Bw, int M, int N, int K,
    short* __restrict__ qkb, short* __restrict__ vtb,
    const float* __restrict__ bias, float* __restrict__ fout) {
  __shared__ short As[128 * 64];  // 16 KB, [row][chunk^(row&7)] of 8-short chunks
  __shared__ short Bs[128 * 64];
  const int tid = threadIdx.x;
  const int lane = tid & 63, wave = tid >> 6;
  const int l15 = lane & 15, quad = lane >> 4;
  const int wr = wave >> 1, wc = wave & 1;
  const int m0 = blockIdx.x * 128, n0 = blockIdx.y * 128;

  // Staging slot: thread = (row r0 = tid>>3, chunk cs = tid&7); it-pass adds
  // +32 rows (swizzle invariant: (r+32)&7 == r&7). Global chunk = cs^(r&7).
  const int r0 = tid >> 3, cs = tid & 7;
  const short* Ag = A + (size_t)(m0 + r0) * K + (cs ^ (r0 & 7)) * 8;
  const short* Bg = Bw + (size_t)(n0 + r0) * K + (cs ^ (r0 & 7)) * 8;

  floatx4 acc[4][4] = {};

  for (int k0 = 0; k0 < K; k0 += 64) {
#pragma unroll
    for (int it = 0; it < 4; ++it) {
      gld_lds16(Ag + k0 + (size_t)(it * 32) * K, As + it * 2048 + tid * 8);
      gld_lds16(Bg + k0 + (size_t)(it * 32) * K, Bs + it * 2048 + tid * 8);
    }
    __syncthreads();
#pragma unroll
    for (int ks = 0; ks < 2; ++ks) {
      short8 af[4], bf[4];
#pragma unroll
      for (int i = 0; i < 4; ++i) {
        const int row = wr * 64 + i * 16 + l15;
        af[i] = *(const short8*)(As + row * 64 +
                                 ((ks * 4 + quad) ^ (l15 & 7)) * 8);
      }
#pragma unroll
      for (int i = 0; i < 4; ++i) {
        const int row = wc * 64 + i * 16 + l15;
        bf[i] = *(const short8*)(Bs + row * 64 +
                                 ((ks * 4 + quad) ^ (l15 & 7)) * 8);
      }
#pragma unroll
      for (int mi = 0; mi < 4; ++mi)
#pragma unroll
        for (int ni = 0; ni < 4; ++ni)
          acc[mi][ni] = mfma16(af[mi], bf[ni], acc[mi][ni]);
    }
    __syncthreads();
  }

  // Epilogue. C/D layout: col = lane&15 (n), row = quad*4 + reg (m). [m89/m91]
#pragma unroll
  for (int mi = 0; mi < 4; ++mi) {
    const int row0 = m0 + wr * 64 + mi * 16 + quad * 4;
#pragma unroll
    for (int ni = 0; ni < 4; ++ni) {
      const int col = n0 + wc * 64 + ni * 16 + l15;
      if constexpr (MODE == 0) {
        if (col < 2 * Cn) {  // wave-uniform branch (128 | 2048 alignment)
#pragma unroll
          for (int r = 0; r < 4; ++r) {
            float v = acc[mi][ni][r];
            if (col < Cn) v *= SCL;  // softmax scale folded into Q
            qkb[(size_t)(row0 + r) * (2 * Cn) + col] = f2bf(v);
          }
        } else {
          const int hc = col - 2 * Cn;
          const int hh = hc >> 6, d = hc & 63;
          const int bb = row0 >> 11, t = row0 & (Tn - 1);
          uint2v pk;
          pk[0] = cvtpk(acc[mi][ni][0], acc[mi][ni][1]);
          pk[1] = cvtpk(acc[mi][ni][2], acc[mi][ni][3]);
          *(uint2v*)(vtb + ((size_t)((bb * Hn + hh) * Dn + d)) * Tn + t) = pk;
        }
      } else {
#pragma unroll
        for (int r = 0; r < 4; ++r)
          fout[(size_t)(row0 + r) * N + col] = acc[mi][ni][r] + bias[col];
      }
    }
  }
}

// ---------------------------------------------------------------- flash attention
// R6 counters: 61.5us with MfmaUtil 25 / VALUBusy 40 / Occupancy 25% ->
// ~36us of dual-pipe idle: 1024 blocks = one dispatch round (no backfill),
// durations 2..32 KV-iters -> wall rides the longest block while freed slots
// idle. R7 (failed 0.283 absmax) bundled the geometry fix with V-direct
// loads + launch_bounds(256,5) (~96 VGPR cap, forced spill around inline-asm
// cvtpk). THIS round isolates: keep ONLY the geometry change, on R6's exact
// proven inner body.
//
// Geometry: Q-tile = 64 rows -> grid dim3(64, 32) = 2048 blocks; wave owns
// ONE 16-row i-frag. Block qh needs exactly qh+1 KV tiles; all 4 waves
// compute every iteration (no intra-block imbalance); qh descending = LPT
// with REAL backfill (2048 > 1024 resident). bh = blockIdx.x keeps XCD
// affinity (linear id % 8 = bh % 8).
//
// Everything else is R6 verbatim: K AND V double-buffered in LDS via
// gld_lds16 (XOR-swizzled on the global address, T2), cvt_pk packing (T12
// primitive), ones-MFMA row sums on the idle MFMA pipe, setprio around MFMA
// clusters (T5), transposed math S^T = K.Q^T / O^T = V^T.P^T, no online max
// (scale folded into Q upstream), per-wave 2KB P scratch with wave-local
// lgkmcnt(0) ordering. LDS 40KB -> 4 blocks/CU capacity (50%); backfill
// should lift time-avg occupancy toward it.
// launch_bounds(256,3): VGPR cap 170 -- proven no-spill regime (R4 lesson:
// tighter bounds spill; halved per-wave state leaves wide headroom here).
__global__ __launch_bounds__(256, 3) void attn_kernel(
    const short* __restrict__ qk, const short* __restrict__ vt,
    short* __restrict__ att) {
  __shared__ short Ks[2][64 * 64];
  __shared__ short Vs[2][64 * 64];
  __shared__ short Ps[4][16 * 64];  // per-wave P-frag scratch (2 KB)

  const int bh = blockIdx.x;       // 0..63; linear id % 8 = bh % 8 (XCD affine)
  const int qh = 31 - blockIdx.y;  // 0..31 descending (longest first, LPT)
  const int b = bh >> 4, h = bh & 15;
  const int tid = threadIdx.x;
  const int lane = tid & 63, wave = tid >> 6;
  const int l15 = lane & 15, quad = lane >> 4;
  const int q0w = qh * 64 + wave * 16;  // this wave's 16 Q rows

  const short* qbase = qk + (size_t)(b * Tn) * 2048 + h * 64;
  const short* kbase = qbase + 1024;
  const short* vbase = vt + (size_t)(bh * 64) * Tn;
  short* pw = Ps[wave];

  // Q^T fragment (B-operand rows [i][c]) in registers for the whole kernel.
  short8 qf[2];
#pragma unroll
  for (int ks = 0; ks < 2; ++ks)
    qf[ks] = *(const short8*)(qbase + (size_t)(q0w + l15) * 2048 + ks * 32 +
                              quad * 8);

  // All-ones bf16 A-operand for MFMA row sums (1.0 = 0x3F80).
  short8 ones;
#pragma unroll
  for (int i = 0; i < 8; ++i) ones[i] = (short)0x3F80;

  floatx4 o[4] = {};     // O^T accumulator [nd], C-layout (row=d, col=i)
  floatx4 sum_acc = {};  // MFMA row-sum acc: D[m][i] identical over m

  const int block_nt = qh + 1;  // KV tiles (uniform across the block's waves)

  const int jr = tid >> 3;  // staging row 0..31 (+32 on 2nd pass)
  const int cl = tid & 7;   // staging LDS chunk

#define STAGE(JT, BUF)                                                       \
  {                                                                          \
    const int j0s = (JT) * 64;                                               \
    _Pragma("unroll") for (int it = 0; it < 2; ++it) {                       \
      const int row = jr + it * 32;                                          \
      const int cg = cl ^ (row & 7);                                         \
      gld_lds16(kbase + (size_t)(j0s + row) * 2048 + cg * 8,                 \
                &Ks[BUF][it * 2048 + tid * 8]);                              \
      gld_lds16(vbase + (size_t)row * Tn + j0s + cg * 8,                     \
                &Vs[BUF][it * 2048 + tid * 8]);                              \
    }                                                                        \
  }

  STAGE(0, 0)
  __syncthreads();

  for (int jt = 0; jt < block_nt; ++jt) {
    const int buf = jt & 1;
    const int j0 = jt * 64;
    if (jt + 1 < block_nt) STAGE(jt + 1, buf ^ 1)

    // ---- S^T = K.Q^T; kf in 2 batches (VGPR economy)
    floatx4 st[4];
#pragma unroll
    for (int nj = 0; nj < 4; ++nj) st[nj] = floatx4{0.f, 0.f, 0.f, 0.f};
#pragma unroll
    for (int half = 0; half < 2; ++half) {
      short8 kfa[2][2];
#pragma unroll
      for (int j2 = 0; j2 < 2; ++j2)
#pragma unroll
        for (int ks = 0; ks < 2; ++ks) {
          const int cld = (ks * 4 + quad) ^ (l15 & 7);
          kfa[j2][ks] = *(const short8*)(
              &Ks[buf][((half * 2 + j2) * 16 + l15) * 64 + cld * 8]);
        }
      __builtin_amdgcn_s_setprio(1);
#pragma unroll
      for (int j2 = 0; j2 < 2; ++j2)
#pragma unroll
        for (int ks = 0; ks < 2; ++ks)
          st[half * 2 + j2] = mfma16(kfa[j2][ks], qf[ks], st[half * 2 + j2]);
      __builtin_amdgcn_s_setprio(0);
    }

    // ---- V^T fragments (A-operand rows [d][j]) from LDS (R6-proven path)
    short8 vf[4][2];
#pragma unroll
    for (int nd = 0; nd < 4; ++nd)
#pragma unroll
      for (int ks = 0; ks < 2; ++ks) {
        const int cld = (ks * 4 + quad) ^ (l15 & 7);
        vf[nd][ks] =
            *(const short8*)(&Vs[buf][(nd * 16 + l15) * 64 + cld * 8]);
      }

    // ---- softmax: exp -> P(bf16 via cvt_pk) -> LDS round-trip (R6 body)
    const bool need_mask = (j0 + 63 > q0w);  // only the diagonal tile
    const int ig = q0w + l15;
#pragma unroll
    for (int nj = 0; nj < 4; ++nj) {
      float p[4];
#pragma unroll
      for (int r = 0; r < 4; ++r) {
        float e = __builtin_amdgcn_exp2f(st[nj][r]);
        if (need_mask) {
          const int jg = j0 + nj * 16 + quad * 4 + r;
          e = (jg > ig) ? 0.f : e;
        }
        p[r] = e;
      }
      // rows j = nj*16+quad*4 .. +3 are consecutive -> one b64 write
      const int c = nj * 2 + (quad >> 1);
      const int cld = c ^ (l15 & 7);
      uint2v pk;
      pk[0] = cvtpk(p[0], p[1]);
      pk[1] = cvtpk(p[2], p[3]);
      *(uint2v*)(&pw[l15 * 64 + cld * 8 + (quad & 1) * 4]) = pk;
    }
    // wave-local: drain P writes (lanes lockstep; DS ops in-order)
    __asm__ volatile("s_waitcnt lgkmcnt(0)" ::: "memory");

    short8 pf[2];
#pragma unroll
    for (int ks = 0; ks < 2; ++ks) {
      const int cld = (ks * 4 + quad) ^ (l15 & 7);
      pf[ks] = *(const short8*)(&pw[l15 * 64 + cld * 8]);
    }
    __builtin_amdgcn_s_setprio(1);
#pragma unroll
    for (int nd = 0; nd < 4; ++nd)
#pragma unroll
      for (int ks = 0; ks < 2; ++ks)
        o[nd] = mfma16(vf[nd][ks], pf[ks], o[nd]);
#pragma unroll
    for (int ks = 0; ks < 2; ++ks) sum_acc = mfma16(ones, pf[ks], sum_acc);
    __builtin_amdgcn_s_setprio(0);
    __asm__ volatile("" ::: "memory");  // P writes of next iter stay after pf

    // Barrier: Ks/Vs[buf] reads done before next iter's STAGE overwrites;
    // the vmcnt(0) drain here also completes STAGE(jt+1).
    __syncthreads();
  }

  // ---- row sums from the ones-MFMA: every reg of sum_acc holds
  // sum_j P[i][j] for this lane's i = l15 -> no shuffles.
  const float inv = 1.0f / sum_acc[0];

  // ---- un-transpose O via per-wave LDS (one 16x64 pass), coalesced stores
#pragma unroll
  for (int nd = 0; nd < 4; ++nd) {
    const int c = nd * 2 + (quad >> 1);
    const int cld = c ^ (l15 & 7);
    uint2v pk;
    pk[0] = cvtpk(o[nd][0] * inv, o[nd][1] * inv);
    pk[1] = cvtpk(o[nd][2] * inv, o[nd][3] * inv);
    *(uint2v*)(&pw[l15 * 64 + cld * 8 + (quad & 1) * 4]) = pk;
  }
  __asm__ volatile("s_waitcnt lgkmcnt(0)" ::: "memory");
#pragma unroll
  for (int ps = 0; ps < 2; ++ps) {
    const int r16 = ps * 8 + (lane >> 3);  // 0..15
    const int cn = lane & 7;
    const int cldr = cn ^ (r16 & 7);
    const short8 val = *(const short8*)(&pw[r16 * 64 + cldr * 8]);
    *(short8*)(att + (size_t)(b * Tn + q0w + r16) * Cn + h * 64 + cn * 8) =
        val;
  }
#undef STAGE
}

// ---------------------------------------------------------------- launch
extern "C" void kernel_launch(void* const* d_in, const int* in_sizes, int n_in,
                              void* d_out, int out_size, void* d_ws,
                              size_t ws_size, hipStream_t stream) {
  const float* x = (const float*)d_in[0];      // [B,T,C]
  const float* w_qkv = (const float*)d_in[1];  // [3C,C]
  const float* w_out = (const float*)d_in[2];  // [C,C]
  const float* b_out = (const float*)d_in[3];  // [C]
  float* out = (float*)d_out;                  // [B,T,C] fp32

  // Workspace layout (75.5 MB total):
  short* xb = (short*)d_ws;                      // 8192*1024  x bf16
  short* wqb = xb + (size_t)8192 * 1024;         // 3072*1024  w_qkv bf16
  short* wob = wqb + (size_t)3072 * 1024;        // 1024*1024  w_out bf16
  short* qkb = wob + (size_t)1024 * 1024;        // 8192*2048  q|k bf16 (q pre-scaled)
  short* vtb = qkb + (size_t)8192 * 2048;        // 64*64*2048 v transposed
  short* att = xb;  // x is dead after GEMM1; reuse for attention output

  // One fused cast: dst segments (xb|wqb|wob) are contiguous in ws.
  cast3_kernel<<<dim3((G_X + G_WQ + G_WO) / 256), 256, 0, stream>>>(
      x, w_qkv, w_out, xb);

  // QKV projection: M=8192, N=3072, K=1024 (proven 2-phase kernel)
  gemm_bt<0><<<dim3(64, 24), 256, 0, stream>>>(xb, wqb, 8192, 3072, 1024, qkb,
                                               vtb, nullptr, nullptr);
  // Flash attention: 2048 blocks (64-row Q tiles), qh descending = LPT with
  // backfill; bh = x keeps XCD affinity.
  attn_kernel<<<dim3(64, 32), 256, 0, stream>>>(qkb, vtb, att);
  // Output projection: M=8192, N=1024, K=1024, +bias, fp32 out
  gemm_bt<1><<<dim3(64, 8), 256, 0, stream>>>(att, wob, 8192, 1024, 1024,
                                              nullptr, nullptr, b_out, out);
}

// Round 9
// 220.441 us; speedup vs baseline: 1.0311x; 1.0311x over previous
//
#include <hip/hip_runtime.h>

// Problem constants (B,T,C,H fixed by the reference).
constexpr int Bn = 4, Tn = 2048, Cn = 1024, Hn = 16, Dn = 64;

typedef __attribute__((ext_vector_type(8))) short short8;
typedef __attribute__((ext_vector_type(4))) float floatx4;
typedef __attribute__((ext_vector_type(2))) unsigned uint2v;
typedef __attribute__((ext_vector_type(4))) unsigned uint4v;

#define DEVFN __device__ __forceinline__

// exp(s/8) = exp2(s * log2e/8); folded into Q at GEMM1 epilogue.
constexpr float SCL = 0.18033688011112042f;

// RTNE float -> bf16 raw bits (inputs are finite; no NaN handling needed).
DEVFN unsigned f2bf_u(float f) {
  unsigned u = __builtin_bit_cast(unsigned, f);
  u += 0x7fffu + ((u >> 16) & 1u);
  return u >> 16;
}
DEVFN short f2bf(float f) { return (short)f2bf_u(f); }

// Packed RTNE f32x2 -> bf16x2 in one VALU op (no builtin on gfx950 -- T12
// primitive). R6: cutting manual pack dropped attn VALUBusy 53% -> 40%.
DEVFN unsigned cvtpk(float lo, float hi) {
  unsigned r;
  asm("v_cvt_pk_bf16_f32 %0, %1, %2" : "=v"(r) : "v"(lo), "v"(hi));
  return r;
}

DEVFN floatx4 mfma16(short8 a, short8 b, floatx4 c) {
  return __builtin_amdgcn_mfma_f32_16x16x32_bf16(a, b, c, 0, 0, 0);
}

// Async global->LDS, 16B/lane. LDS dest must be wave-uniform base + lane*16.
DEVFN void gld_lds16(const void* g, void* l) {
  __builtin_amdgcn_global_load_lds(
      (const __attribute__((address_space(1))) unsigned*)g,
      (__attribute__((address_space(3))) unsigned*)l, 16, 0, 0);
}

// ---------------------------------------------------------------- fused fp32->bf16
// One kernel casts all three inputs; destinations are contiguous in ws
// (xb | wqb | wob), so dst indexes by the global group id directly.
constexpr int G_X = 8192 * 1024 / 8;   // 1048576 groups of 8
constexpr int G_WQ = 3072 * 1024 / 8;  // 393216
constexpr int G_WO = 1024 * 1024 / 8;  // 131072
__global__ __launch_bounds__(256) void cast3_kernel(
    const float* __restrict__ x, const float* __restrict__ wq,
    const float* __restrict__ wo, short* __restrict__ dst) {
  const int i = blockIdx.x * 256 + threadIdx.x;
  const float* src;
  int rel;
  if (i < G_X) {
    src = x; rel = i;
  } else if (i < G_X + G_WQ) {
    src = wq; rel = i - G_X;
  } else {
    src = wo; rel = i - (G_X + G_WQ);
  }
  const floatx4* p = (const floatx4*)src + (size_t)rel * 2;
  floatx4 a = p[0], b = p[1];
  uint4v r;
  r[0] = cvtpk(a[0], a[1]);
  r[1] = cvtpk(a[2], a[3]);
  r[2] = cvtpk(b[0], b[1]);
  r[3] = cvtpk(b[2], b[3]);
  ((uint4v*)dst)[i] = r;
}

// ---------------------------------------------------------------- GEMM  Y = A @ B^T
// 2-phase 128x128 tile, BK=64, XOR-swizzled LDS (16B chunk ^= row&7) applied
// on the stager's GLOBAL address (fragment b128 reads conflict-free while the
// LDS side keeps gld_lds16's required uniform+lane*16 mapping).
// R1-R4 post-mortem: an 8-phase 256^2 counted-vmcnt port (m201 template) was
// tried for MODE 0 and LOST (83-107us vs 76us here): 128KB LDS -> 1 block/CU
// -> zero TLP, and at K=1024 (16 K-tiles) + 1.5 grid rounds the lockstep
// barrier chain stalls on every L2 miss. Keep the 2-phase local optimum.
// MODE 0: QKV projection. Q cols [0,1024) PRE-SCALED by log2e/8 (softmax
//         fold). Q|K -> qkb [M,2048]; V cols [2048,3072) written transposed
//         into vtb[B][H][D][T] (b64-packed: consecutive acc regs = consecutive t).
// MODE 1: output projection: fp32 out + bias.
template <int MODE>
__global__ __launch_bounds__(256, 2) void gemm_bt(
    const short* __restrict__ A, const short* __restrict__ Bw, int M, int N, int K,
    short* __restrict__ qkb, short* __restrict__ vtb,
    const float* __restrict__ bias, float* __restrict__ fout) {
  __shared__ short As[128 * 64];  // 16 KB, [row][chunk^(row&7)] of 8-short chunks
  __shared__ short Bs[128 * 64];
  const int tid = threadIdx.x;
  const int lane = tid & 63, wave = tid >> 6;
  const int l15 = lane & 15, quad = lane >> 4;
  const int wr = wave >> 1, wc = wave & 1;
  const int m0 = blockIdx.x * 128, n0 = blockIdx.y * 128;

  // Staging slot: thread = (row r0 = tid>>3, chunk cs = tid&7); it-pass adds
  // +32 rows (swizzle invariant: (r+32)&7 == r&7). Global chunk = cs^(r&7).
  const int r0 = tid >> 3, cs = tid & 7;
  const short* Ag = A + (size_t)(m0 + r0) * K + (cs ^ (r0 & 7)) * 8;
  const short* Bg = Bw + (size_t)(n0 + r0) * K + (cs ^ (r0 & 7)) * 8;

  floatx4 acc[4][4] = {};

  for (int k0 = 0; k0 < K; k0 += 64) {
#pragma unroll
    for (int it = 0; it < 4; ++it) {
      gld_lds16(Ag + k0 + (size_t)(it * 32) * K, As + it * 2048 + tid * 8);
      gld_lds16(Bg + k0 + (size_t)(it * 32) * K, Bs + it * 2048 + tid * 8);
    }
    __syncthreads();
#pragma unroll
    for (int ks = 0; ks < 2; ++ks) {
      short8 af[4], bf[4];
#pragma unroll
      for (int i = 0; i < 4; ++i) {
        const int row = wr * 64 + i * 16 + l15;
        af[i] = *(const short8*)(As + row * 64 +
                                 ((ks * 4 + quad) ^ (l15 & 7)) * 8);
      }
#pragma unroll
      for (int i = 0; i < 4; ++i) {
        const int row = wc * 64 + i * 16 + l15;
        bf[i] = *(const short8*)(Bs + row * 64 +
                                 ((ks * 4 + quad) ^ (l15 & 7)) * 8);
      }
#pragma unroll
      for (int mi = 0; mi < 4; ++mi)
#pragma unroll
        for (int ni = 0; ni < 4; ++ni)
          acc[mi][ni] = mfma16(af[mi], bf[ni], acc[mi][ni]);
    }
    __syncthreads();
  }

  // Epilogue. C/D layout: col = lane&15 (n), row = quad*4 + reg (m). [m89/m91]
#pragma unroll
  for (int mi = 0; mi < 4; ++mi) {
    const int row0 = m0 + wr * 64 + mi * 16 + quad * 4;
#pragma unroll
    for (int ni = 0; ni < 4; ++ni) {
      const int col = n0 + wc * 64 + ni * 16 + l15;
      if constexpr (MODE == 0) {
        if (col < 2 * Cn) {  // wave-uniform branch (128 | 2048 alignment)
#pragma unroll
          for (int r = 0; r < 4; ++r) {
            float v = acc[mi][ni][r];
            if (col < Cn) v *= SCL;  // softmax scale folded into Q
            qkb[(size_t)(row0 + r) * (2 * Cn) + col] = f2bf(v);
          }
        } else {
          const int hc = col - 2 * Cn;
          const int hh = hc >> 6, d = hc & 63;
          const int bb = row0 >> 11, t = row0 & (Tn - 1);
          uint2v pk;
          pk[0] = cvtpk(acc[mi][ni][0], acc[mi][ni][1]);
          pk[1] = cvtpk(acc[mi][ni][2], acc[mi][ni][3]);
          *(uint2v*)(vtb + ((size_t)((bb * Hn + hh) * Dn + d)) * Tn + t) = pk;
        }
      } else {
#pragma unroll
        for (int r = 0; r < 4; ++r)
          fout[(size_t)(row0 + r) * N + col] = acc[mi][ni][r] + bias[col];
      }
    }
  }
}

// ---------------------------------------------------------------- flash attention
// R6-proven configuration (61.5us measured) -- restored verbatim after two
// structural excursions regressed:
//  R7: 64-row Q-tiles + V-direct-from-L2 + launch_bounds(256,5) -> absmax
//      0.283 FAIL (V-direct or spill around inline-asm cvtpk corrupted PV).
//  R8: 64-row Q-tiles alone (R6 body) -> PASSED but 67.5us: occupancy rose
//      25->35% yet duration worsened. Block-iters doubled (272->528 per bh,
//      FETCH 27->33.8MB) while each iteration keeps the same fixed cost
//      (stage DMA, barrier+vmcnt drain, softmax chain). Per-iteration
//      overhead, not wave occupancy, is the binding constraint.
//
// Structure: block = 4 waves; wave owns 32 Q rows (2 i-frags). KV tile = 64,
// K AND V double-buffered in LDS via gld_lds16 (XOR-swizzle 16B chunk ^=
// row&7 applied on the stager's GLOBAL address, T2). Transposed math:
// S^T = K.Q^T, O^T = V^T.P^T; no online max (softmax scale folded into Q
// upstream). P round-trip through per-wave 2KB LDS per i-frag (LDS 40KB ->
// 4 blocks/CU). cvt_pk packing (T12 primitive); ones-MFMA row sums (the
// idle MFMA pipe does the reduction; no cross-lane shuffles); setprio
// around MFMA clusters (T5, independent-block regime, m191).
//
// Grid dim3(64,16): bh = x; qt from a balance LUT on g = blockIdx.y.
// 1024 blocks fill exactly the 1024 resident slots (4/CU); nibble LUT
// 0x32104567ba98cdef makes every dispatch-quartile column (g,g+4,g+8,g+12)
// sum to 30 -> uniform 68 tiles/CU. Heaviest first; linear id % 8 = bh % 8
// keeps one bh per XCD. Heuristic only -- correctness never depends on it.
// launch_bounds(256,3): VGPR cap 170 -- proven no-spill regime (R4/R7
// lessons: tighter bounds spill scratch to HBM). Don't tighten it.
__global__ __launch_bounds__(256, 3) void attn_kernel(
    const short* __restrict__ qk, const short* __restrict__ vt,
    short* __restrict__ att) {
  __shared__ short Ks[2][64 * 64];
  __shared__ short Vs[2][64 * 64];
  __shared__ short Ps[4][16 * 64];  // per-wave P-frag scratch (2 KB)

  const int bh = blockIdx.x;  // 0..63
  // Balance LUT: g -> qt, columns (g, g+4, g+8, g+12) each sum to 30.
  const int qt =
      (int)((0x32104567ba98cdefULL >> (blockIdx.y * 4)) & 0xFULL);
  const int b = bh >> 4, h = bh & 15;
  const int tid = threadIdx.x;
  const int lane = tid & 63, wave = tid >> 6;
  const int l15 = lane & 15, quad = lane >> 4;
  const int q0w = qt * 128 + wave * 32;  // this wave's 32 Q rows

  const short* qbase = qk + (size_t)(b * Tn) * 2048 + h * 64;
  const short* kbase = qbase + 1024;
  const short* vbase = vt + (size_t)(bh * 64) * Tn;
  short* pw = Ps[wave];

  // Q^T fragments (B-operand rows [i][c]) in registers for the whole kernel.
  short8 qf[2][2];
#pragma unroll
  for (int f = 0; f < 2; ++f)
#pragma unroll
    for (int ks = 0; ks < 2; ++ks)
      qf[f][ks] = *(const short8*)(qbase + (size_t)(q0w + f * 16 + l15) * 2048 +
                                   ks * 32 + quad * 8);

  // All-ones bf16 A-operand for MFMA row sums (1.0 = 0x3F80).
  short8 ones;
#pragma unroll
  for (int i = 0; i < 8; ++i) ones[i] = (short)0x3F80;

  floatx4 o[2][4] = {};     // O^T accumulator [f][nd], C-layout (row=d, col=i)
  floatx4 sum_acc[2] = {};  // MFMA row-sum acc: D[m][i] identical over m

  const int wave_nt = ((q0w + 31) >> 6) + 1;  // tiles this wave computes
  const int block_nt = 2 * qt + 2;            // loop count (uniform per block)

  const int jr = tid >> 3;  // staging row 0..31 (+32 on 2nd pass)
  const int cl = tid & 7;   // staging LDS chunk

#define STAGE(JT, BUF)                                                       \
  {                                                                          \
    const int j0s = (JT) * 64;                                               \
    _Pragma("unroll") for (int it = 0; it < 2; ++it) {                       \
      const int row = jr + it * 32;                                          \
      const int cg = cl ^ (row & 7);                                         \
      gld_lds16(kbase + (size_t)(j0s + row) * 2048 + cg * 8,                 \
                &Ks[BUF][it * 2048 + tid * 8]);                              \
      gld_lds16(vbase + (size_t)row * Tn + j0s + cg * 8,                     \
                &Vs[BUF][it * 2048 + tid * 8]);                              \
    }                                                                        \
  }

  STAGE(0, 0)
  __syncthreads();

  for (int jt = 0; jt < block_nt; ++jt) {
    const int buf = jt & 1;
    if (jt + 1 < block_nt) STAGE(jt + 1, buf ^ 1)

    if (jt < wave_nt) {
      const int j0 = jt * 64;

      // ---- S^T = K.Q^T for both i-frags; kf in 2 batches (VGPR economy)
      floatx4 st[2][4];
#pragma unroll
      for (int f = 0; f < 2; ++f)
#pragma unroll
        for (int nj = 0; nj < 4; ++nj) st[f][nj] = floatx4{0.f, 0.f, 0.f, 0.f};
#pragma unroll
      for (int half = 0; half < 2; ++half) {
        short8 kfa[2][2];
#pragma unroll
        for (int j2 = 0; j2 < 2; ++j2)
#pragma unroll
          for (int ks = 0; ks < 2; ++ks) {
            const int cld = (ks * 4 + quad) ^ (l15 & 7);
            kfa[j2][ks] = *(const short8*)(
                &Ks[buf][((half * 2 + j2) * 16 + l15) * 64 + cld * 8]);
          }
        __builtin_amdgcn_s_setprio(1);
#pragma unroll
        for (int f = 0; f < 2; ++f)
#pragma unroll
          for (int j2 = 0; j2 < 2; ++j2)
#pragma unroll
            for (int ks = 0; ks < 2; ++ks)
              st[f][half * 2 + j2] =
                  mfma16(kfa[j2][ks], qf[f][ks], st[f][half * 2 + j2]);
        __builtin_amdgcn_s_setprio(0);
      }

      // ---- V^T fragments (A-operand rows [d][j]), shared by both i-frags
      short8 vf[4][2];
#pragma unroll
      for (int nd = 0; nd < 4; ++nd)
#pragma unroll
        for (int ks = 0; ks < 2; ++ks) {
          const int cld = (ks * 4 + quad) ^ (l15 & 7);
          vf[nd][ks] =
              *(const short8*)(&Vs[buf][(nd * 16 + l15) * 64 + cld * 8]);
        }

      // ---- per i-frag: exp -> P(bf16 via cvt_pk) -> LDS -> PV + ones-sum
#pragma unroll
      for (int f = 0; f < 2; ++f) {
        const bool need_mask = (j0 + 63 > q0w + f * 16);
        const int ig = q0w + f * 16 + l15;
#pragma unroll
        for (int nj = 0; nj < 4; ++nj) {
          float p[4];
#pragma unroll
          for (int r = 0; r < 4; ++r) {
            float e = __builtin_amdgcn_exp2f(st[f][nj][r]);
            if (need_mask) {
              const int jg = j0 + nj * 16 + quad * 4 + r;
              e = (jg > ig) ? 0.f : e;
            }
            p[r] = e;
          }
          // rows j = nj*16+quad*4 .. +3 are consecutive -> one b64 write
          const int c = nj * 2 + (quad >> 1);
          const int cld = c ^ (l15 & 7);
          uint2v pk;
          pk[0] = cvtpk(p[0], p[1]);
          pk[1] = cvtpk(p[2], p[3]);
          *(uint2v*)(&pw[l15 * 64 + cld * 8 + (quad & 1) * 4]) = pk;
        }
        // wave-local: drain P writes (lanes lockstep; DS ops in-order)
        __asm__ volatile("s_waitcnt lgkmcnt(0)" ::: "memory");

        short8 pf[2];
#pragma unroll
        for (int ks = 0; ks < 2; ++ks) {
          const int cld = (ks * 4 + quad) ^ (l15 & 7);
          pf[ks] = *(const short8*)(&pw[l15 * 64 + cld * 8]);
        }
        __builtin_amdgcn_s_setprio(1);
#pragma unroll
        for (int nd = 0; nd < 4; ++nd)
#pragma unroll
          for (int ks = 0; ks < 2; ++ks)
            o[f][nd] = mfma16(vf[nd][ks], pf[ks], o[f][nd]);
#pragma unroll
        for (int ks = 0; ks < 2; ++ks)
          sum_acc[f] = mfma16(ones, pf[ks], sum_acc[f]);
        __builtin_amdgcn_s_setprio(0);
        __asm__ volatile("" ::: "memory");  // keep f=1 P writes after pf reads
      }
    }
    __syncthreads();
  }

  // ---- row sums came out of the ones-MFMA: every reg of sum_acc[f] holds
  // sum_j P[i][j] for this lane's i = l15 (identical across m) -> no shuffles.
  float inv[2];
#pragma unroll
  for (int f = 0; f < 2; ++f) inv[f] = 1.0f / sum_acc[f][0];

  // ---- un-transpose O via per-wave LDS (16x64 per pass), coalesced stores
#pragma unroll
  for (int f = 0; f < 2; ++f) {
#pragma unroll
    for (int nd = 0; nd < 4; ++nd) {
      const int c = nd * 2 + (quad >> 1);
      const int cld = c ^ (l15 & 7);
      uint2v pk;
      pk[0] = cvtpk(o[f][nd][0] * inv[f], o[f][nd][1] * inv[f]);
      pk[1] = cvtpk(o[f][nd][2] * inv[f], o[f][nd][3] * inv[f]);
      *(uint2v*)(&pw[l15 * 64 + cld * 8 + (quad & 1) * 4]) = pk;
    }
    __asm__ volatile("s_waitcnt lgkmcnt(0)" ::: "memory");
#pragma unroll
    for (int ps = 0; ps < 2; ++ps) {
      const int r16 = ps * 8 + (lane >> 3);  // 0..15
      const int cn = lane & 7;
      const int cldr = cn ^ (r16 & 7);
      const short8 val = *(const short8*)(&pw[r16 * 64 + cldr * 8]);
      *(short8*)(att + (size_t)(b * Tn + q0w + f * 16 + r16) * Cn + h * 64 +
                 cn * 8) = val;
    }
    __asm__ volatile("" ::: "memory");  // f=1 writes stay after f=0 reads
  }
#undef STAGE
}

// ---------------------------------------------------------------- launch
extern "C" void kernel_launch(void* const* d_in, const int* in_sizes, int n_in,
                              void* d_out, int out_size, void* d_ws,
                              size_t ws_size, hipStream_t stream) {
  const float* x = (const float*)d_in[0];      // [B,T,C]
  const float* w_qkv = (const float*)d_in[1];  // [3C,C]
  const float* w_out = (const float*)d_in[2];  // [C,C]
  const float* b_out = (const float*)d_in[3];  // [C]
  float* out = (float*)d_out;                  // [B,T,C] fp32

  // Workspace layout (75.5 MB total):
  short* xb = (short*)d_ws;                      // 8192*1024  x bf16
  short* wqb = xb + (size_t)8192 * 1024;         // 3072*1024  w_qkv bf16
  short* wob = wqb + (size_t)3072 * 1024;        // 1024*1024  w_out bf16
  short* qkb = wob + (size_t)1024 * 1024;        // 8192*2048  q|k bf16 (q pre-scaled)
  short* vtb = qkb + (size_t)8192 * 2048;        // 64*64*2048 v transposed
  short* att = xb;  // x is dead after GEMM1; reuse for attention output

  // One fused cast: dst segments (xb|wqb|wob) are contiguous in ws.
  cast3_kernel<<<dim3((G_X + G_WQ + G_WO) / 256), 256, 0, stream>>>(
      x, w_qkv, w_out, xb);

  // QKV projection: M=8192, N=3072, K=1024 (proven 2-phase kernel)
  gemm_bt<0><<<dim3(64, 24), 256, 0, stream>>>(xb, wqb, 8192, 3072, 1024, qkb,
                                               vtb, nullptr, nullptr);
  // Flash attention: bh = x (XCD-affine), qt via per-CU balance LUT
  attn_kernel<<<dim3(64, 16), 256, 0, stream>>>(qkb, vtb, att);
  // Output projection: M=8192, N=1024, K=1024, +bias, fp32 out
  gemm_bt<1><<<dim3(64, 8), 256, 0, stream>>>(att, wob, 8192, 1024, 1024,
                                              nullptr, nullptr, b_out, out);
}